// Round 8
// baseline (158.913 us; speedup 1.0000x reference)
//
#include <hip/hip_runtime.h>
#include <math.h>

#define HH 256
#define NN 64
#define LL 4096
#define BB 8
#define TK 32            // tokens per gconv block
#define NCH (LL / TK)    // 128 chunks per batch

// ws layout (floats):
//   Ktrev (float [L][H])   @ 0        (1048576)   Ktrev[i][h] = K[h][L-1-i]
//   ypart (float [B][NCH][H]) @ 1048576 (262144)

// k1: K-materialization, one block per h (R7's proven spill-free scheme):
//   K[h,l] = Re( sum_n w[h,n] * dA[h,n]^l ),  w = 2*C0*dB
//   wave w owns l-range [512w,512w+512), lane owns l%64, n serial; pow
//   table dA_n^lane in padded LDS; store TRANSPOSED+reversed: Ktrev[L-1-l][h]
//   (scattered 4B stores, ~4MB total -- accepted cost for the coalesced
//   h-parallel reads in k2).
__global__ __launch_bounds__(512) void kmat_kernel(
    const float* __restrict__ log_dt, const float* __restrict__ A_log_re,
    const float* __restrict__ A_im, const float* __restrict__ B_re,
    const float* __restrict__ B_im, const float* __restrict__ C_re,
    const float* __restrict__ C_im, float* __restrict__ Ktrev) {
    __shared__ struct {
        float powR[64][65]; float powI[64][65];
        float2 dAt[64]; float2 e64t[64]; float2 W2[8][64];
    } sk;
    int t = threadIdx.x;
    int h = blockIdx.x;
    int w = __builtin_amdgcn_readfirstlane(t >> 6);   // wave id 0..7
    int lane = t & 63;
    // -- stage 1 (wave 0): per-n constants --
    if (t < NN) {
        int n = t;
        int idx = h * NN + n;
        float dt = expf(log_dt[h]);
        float Are = -expf(A_log_re[idx]);
        float Aim = A_im[idx];
        float ea = expf(dt * Are);
        float sn, cs;
        sincosf(dt * Aim, &sn, &cs);
        float dAre = ea * cs, dAim = ea * sn;
        float numre = dAre - 1.0f, numim = dAim;
        float den = Are * Are + Aim * Aim;
        float qre = (numre * Are + numim * Aim) / den;
        float qim = (numim * Are - numre * Aim) / den;
        float bre = B_re[idx], bim = B_im[idx];
        float dBre = bre * qre - bim * qim;
        float dBim = bre * qim + bim * qre;
        float cre = C_re[idx], cim = C_im[idx];
        float wre = 2.0f * (cre * dBre - cim * dBim);
        float wim = 2.0f * (cre * dBim + cim * dBre);
        sk.dAt[n] = make_float2(dAre, dAim);
        // e64 = dA^64 (6 squarings)
        float pr = dAre, pi = dAim;
        #pragma unroll
        for (int kq = 0; kq < 6; ++kq) {
            float nr = pr * pr - pi * pi;
            pi = 2.0f * pr * pi; pr = nr;
        }
        sk.e64t[n] = make_float2(pr, pi);
        // dA^512 = 3 more squarings
        #pragma unroll
        for (int kq = 0; kq < 3; ++kq) {
            float nr = pr * pr - pi * pi;
            pi = 2.0f * pr * pi; pr = nr;
        }
        // W2[k][n] = w_n * dA^(512k)
        float qr2 = wre, qi2 = wim;
        #pragma unroll
        for (int kk = 0; kk < 8; ++kk) {
            sk.W2[kk][n] = make_float2(qr2, qi2);
            float nr = qr2 * pr - qi2 * pi, ni = qr2 * pi + qi2 * pr;
            qr2 = nr; qi2 = ni;
        }
    }
    __syncthreads();
    // -- stage 2 (all waves): pow table, wave w fills rows 8w..8w+7 --
    {
        float2 a = sk.dAt[lane];             // dA_n, n = lane
        float br = a.x, bi = a.y;            // -> dA^8
        #pragma unroll
        for (int kq = 0; kq < 3; ++kq) {
            float nr = br * br - bi * bi;
            bi = 2.0f * br * bi; br = nr;
        }
        float pr = 1.0f, pi = 0.0f;          // d8^w (w uniform)
        #pragma unroll
        for (int bit = 0; bit < 3; ++bit) {
            if ((w >> bit) & 1) {
                float tr = pr * br - pi * bi;
                pi = pr * bi + pi * br; pr = tr;
            }
            float t2 = br * br - bi * bi;
            bi = 2.0f * br * bi; br = t2;
        }
        #pragma unroll
        for (int i = 0; i < 8; ++i) {        // pow[8w+i][n] = dA_n^(8w+i)
            sk.powR[8 * w + i][lane] = pr;
            sk.powI[8 * w + i][lane] = pi;
            float tr = pr * a.x - pi * a.y;
            pi = pr * a.y + pi * a.x; pr = tr;
        }
    }
    __syncthreads();
    // -- stage 3: thread owns l = 512w + 64j + lane, n serial --
    float kacc[8];
    #pragma unroll
    for (int j = 0; j < 8; ++j) kacc[j] = 0.0f;
    #pragma unroll 2
    for (int n = 0; n < NN; ++n) {
        float Pr = sk.powR[lane][n];         // conflict-free (pad 65)
        float Pi = sk.powI[lane][n];
        float2 E = sk.e64t[n];               // uniform broadcast
        float2 Wn = sk.W2[w][n];             // uniform broadcast
        float vr = Wn.x * Pr - Wn.y * Pi;
        float vi = Wn.x * Pi + Wn.y * Pr;
        #pragma unroll
        for (int j = 0; j < 8; ++j) {
            kacc[j] += vr;
            float tr = vr * E.x - vi * E.y;
            vi = vr * E.y + vi * E.x; vr = tr;
        }
    }
    // -- store transposed + reversed --
    #pragma unroll
    for (int j = 0; j < 8; ++j) {
        int l = w * 512 + j * 64 + lane;
        Ktrev[(long)(LL - 1 - l) * HH + h] = kacc[j];
    }
}

// k2: fused gather-conv -- no u materialization. Block = (b, 32-token
// chunk). Stage Ktrev slice [32][256] linearly via global_load_lds (LDS
// read Kls[l*256+t]: lanes consecutive -> conflict-free); stream emb rows
// coalesced; 32 FMA/thread; write per-chunk partial.
__global__ __launch_bounds__(256) void gconv_kernel(
    const int* __restrict__ ids, const float* __restrict__ emb,
    const float* __restrict__ Ktrev, float* __restrict__ ypart) {
    __shared__ float Kls[TK * HH];   // 32 KB
    __shared__ int idsl[TK];
    int t = threadIdx.x;
    int b = blockIdx.x >> 7;
    int c = blockIdx.x & (NCH - 1);
    int i0 = c * TK;
    int wv = t >> 6, lane = t & 63;
    if (t < TK) idsl[t] = ids[b * LL + i0 + t];
    // wave wv stages rows [8wv, 8wv+8): one global_load_lds (1KB) per row
    {
        const float* src = Ktrev + (long)i0 * HH;
        #pragma unroll
        for (int r = 0; r < 8; ++r) {
            int row = wv * 8 + r;
            __builtin_amdgcn_global_load_lds(
                (const __attribute__((address_space(1))) void*)
                    (src + row * HH + lane * 4),
                (__attribute__((address_space(3))) void*)(&Kls[row * HH]),
                16, 0, 0);
        }
    }
    __syncthreads();   // drains vmcnt + lgkmcnt
    float acc = 0.0f;
    #pragma unroll 8
    for (int l = 0; l < TK; ++l) {
        int id = idsl[l];                        // uniform LDS broadcast
        float v = emb[(long)id * HH + t];        // coalesced 1KB/256thr
        acc = fmaf(v, Kls[l * HH + t], acc);     // conflict-free ds_read
    }
    ypart[((long)(b * NCH + c)) * HH + t] = acc;
}

// k3: reduce partials + D-term + GELU + projection + GLU. One block per b.
__global__ __launch_bounds__(512) void out_kernel(
    const float* __restrict__ ypart, const int* __restrict__ ids,
    const float* __restrict__ emb, const float* __restrict__ Dv,
    const float* __restrict__ W, const float* __restrict__ bvec,
    float* __restrict__ out) {
    __shared__ float red[8][HH];   // 8 KB wave partials
    __shared__ float gs[HH];
    __shared__ float zb[2 * HH];
    int t = threadIdx.x;
    int b = blockIdx.x;
    int wv = t >> 6, lane = t & 63;
    // wave wv sums chunks [16wv, 16wv+16), float4 over h
    float4 s4 = make_float4(0.f, 0.f, 0.f, 0.f);
    const float4* yp4 = (const float4*)(ypart + (long)b * NCH * HH);
    #pragma unroll 4
    for (int cc = 0; cc < 16; ++cc) {
        float4 v = yp4[(wv * 16 + cc) * 64 + lane];
        s4.x += v.x; s4.y += v.y; s4.z += v.z; s4.w += v.w;
    }
    *(float4*)&red[wv][lane * 4] = s4;
    __syncthreads();
    if (t < HH) {
        float s = 0.0f;
        #pragma unroll
        for (int w2 = 0; w2 < 8; ++w2) s += red[w2][t];
        int idl = ids[b * LL + LL - 1];
        float ul = emb[(long)idl * HH + t];
        float y = s + ul * Dv[t];
        gs[t] = 0.5f * y * (1.0f + erff(y * 0.70710678118654752f));
    }
    __syncthreads();
    // projection: wave wv owns o in [64wv, 64wv+64), wave-dot per o
    #pragma unroll 2
    for (int oo = 0; oo < 64; ++oo) {
        int o = wv * 64 + oo;
        float4 wr = ((const float4*)(W + o * HH))[lane];
        float4 gr = ((const float4*)gs)[lane];
        float p = wr.x * gr.x + wr.y * gr.y + wr.z * gr.z + wr.w * gr.w;
        #pragma unroll
        for (int m = 32; m > 0; m >>= 1) p += __shfl_xor(p, m);
        if (lane == 0) zb[o] = p + bvec[o];
    }
    __syncthreads();
    if (t < HH) {
        float z1 = zb[t];
        float z2 = zb[t + HH];
        out[b * HH + t] = z1 * (1.0f / (1.0f + expf(-z2)));
    }
}

extern "C" void kernel_launch(void* const* d_in, const int* in_sizes, int n_in,
                              void* d_out, int out_size, void* d_ws, size_t ws_size,
                              hipStream_t stream) {
    const int* input_ids = (const int*)d_in[0];
    const float* embedding = (const float*)d_in[1];
    const float* log_dt = (const float*)d_in[2];
    const float* A_log_re = (const float*)d_in[3];
    const float* A_im = (const float*)d_in[4];
    const float* B_re = (const float*)d_in[5];
    const float* B_im = (const float*)d_in[6];
    const float* C_re = (const float*)d_in[7];
    const float* C_im = (const float*)d_in[8];
    const float* D = (const float*)d_in[9];
    const float* W_out = (const float*)d_in[10];
    const float* b_out = (const float*)d_in[11];
    float* out = (float*)d_out;

    float* ws = (float*)d_ws;
    float* Ktrev = ws;                            // L*H floats
    float* ypart = ws + 1048576;                  // B*NCH*H floats

    kmat_kernel<<<HH, 512, 0, stream>>>(
        log_dt, A_log_re, A_im, B_re, B_im, C_re, C_im, Ktrev);

    gconv_kernel<<<BB * NCH, 256, 0, stream>>>(
        input_ids, embedding, Ktrev, ypart);

    out_kernel<<<BB, 512, 0, stream>>>(
        ypart, input_ids, embedding, D, W_out, b_out, out);
}

// Round 9
// 122.433 us; speedup vs baseline: 1.2980x; 1.2980x over previous
//
#include <hip/hip_runtime.h>
#include <math.h>

#define HH 256
#define NN 64
#define LL 4096
#define BB 8
#define TK 32            // tokens per gconv block
#define NCH (LL / TK)    // 128 chunks per batch

// ws layout (floats):
//   Ktrev (float [L][H])   @ 0        (1048576)   Ktrev[i][h] = K[h][L-1-i]
//   y     (float [B][H])   @ 1048576  (2048)      atomic-accumulated conv

// k1: K-materialization, one block per h (R7's proven spill-free scheme):
//   K[h,l] = Re( sum_n w[h,n] * dA[h,n]^l ),  w = 2*C0*dB
//   wave w owns l-range [512w,512w+512), lane owns l%64, n serial; pow
//   table dA_n^lane in padded LDS; store TRANSPOSED+reversed. Block 0 also
//   zero-inits y (stream order: lands before gconv's atomics).
__global__ __launch_bounds__(512) void kmat_kernel(
    const float* __restrict__ log_dt, const float* __restrict__ A_log_re,
    const float* __restrict__ A_im, const float* __restrict__ B_re,
    const float* __restrict__ B_im, const float* __restrict__ C_re,
    const float* __restrict__ C_im, float* __restrict__ Ktrev,
    float* __restrict__ y) {
    __shared__ struct {
        float powR[64][65]; float powI[64][65];
        float2 dAt[64]; float2 e64t[64]; float2 W2[8][64];
    } sk;
    int t = threadIdx.x;
    int h = blockIdx.x;
    int w = __builtin_amdgcn_readfirstlane(t >> 6);   // wave id 0..7
    int lane = t & 63;
    if (h == 0) {   // zero y for this iteration (ws is re-poisoned each iter)
        #pragma unroll
        for (int i = 0; i < BB * HH / 512; ++i) y[i * 512 + t] = 0.0f;
    }
    // -- stage 1 (wave 0): per-n constants --
    if (t < NN) {
        int n = t;
        int idx = h * NN + n;
        float dt = expf(log_dt[h]);
        float Are = -expf(A_log_re[idx]);
        float Aim = A_im[idx];
        float ea = expf(dt * Are);
        float sn, cs;
        sincosf(dt * Aim, &sn, &cs);
        float dAre = ea * cs, dAim = ea * sn;
        float numre = dAre - 1.0f, numim = dAim;
        float den = Are * Are + Aim * Aim;
        float qre = (numre * Are + numim * Aim) / den;
        float qim = (numim * Are - numre * Aim) / den;
        float bre = B_re[idx], bim = B_im[idx];
        float dBre = bre * qre - bim * qim;
        float dBim = bre * qim + bim * qre;
        float cre = C_re[idx], cim = C_im[idx];
        float wre = 2.0f * (cre * dBre - cim * dBim);
        float wim = 2.0f * (cre * dBim + cim * dBre);
        sk.dAt[n] = make_float2(dAre, dAim);
        // e64 = dA^64 (6 squarings)
        float pr = dAre, pi = dAim;
        #pragma unroll
        for (int kq = 0; kq < 6; ++kq) {
            float nr = pr * pr - pi * pi;
            pi = 2.0f * pr * pi; pr = nr;
        }
        sk.e64t[n] = make_float2(pr, pi);
        // dA^512 = 3 more squarings
        #pragma unroll
        for (int kq = 0; kq < 3; ++kq) {
            float nr = pr * pr - pi * pi;
            pi = 2.0f * pr * pi; pr = nr;
        }
        // W2[k][n] = w_n * dA^(512k)
        float qr2 = wre, qi2 = wim;
        #pragma unroll
        for (int kk = 0; kk < 8; ++kk) {
            sk.W2[kk][n] = make_float2(qr2, qi2);
            float nr = qr2 * pr - qi2 * pi, ni = qr2 * pi + qi2 * pr;
            qr2 = nr; qi2 = ni;
        }
    }
    __syncthreads();
    // -- stage 2 (all waves): pow table, wave w fills rows 8w..8w+7 --
    {
        float2 a = sk.dAt[lane];             // dA_n, n = lane
        float br = a.x, bi = a.y;            // -> dA^8
        #pragma unroll
        for (int kq = 0; kq < 3; ++kq) {
            float nr = br * br - bi * bi;
            bi = 2.0f * br * bi; br = nr;
        }
        float pr = 1.0f, pi = 0.0f;          // d8^w (w uniform)
        #pragma unroll
        for (int bit = 0; bit < 3; ++bit) {
            if ((w >> bit) & 1) {
                float tr = pr * br - pi * bi;
                pi = pr * bi + pi * br; pr = tr;
            }
            float t2 = br * br - bi * bi;
            bi = 2.0f * br * bi; br = t2;
        }
        #pragma unroll
        for (int i = 0; i < 8; ++i) {        // pow[8w+i][n] = dA_n^(8w+i)
            sk.powR[8 * w + i][lane] = pr;
            sk.powI[8 * w + i][lane] = pi;
            float tr = pr * a.x - pi * a.y;
            pi = pr * a.y + pi * a.x; pr = tr;
        }
    }
    __syncthreads();
    // -- stage 3: thread owns l = 512w + 64j + lane, n serial --
    float kacc[8];
    #pragma unroll
    for (int j = 0; j < 8; ++j) kacc[j] = 0.0f;
    #pragma unroll 2
    for (int n = 0; n < NN; ++n) {
        float Pr = sk.powR[lane][n];         // conflict-free (pad 65)
        float Pi = sk.powI[lane][n];
        float2 E = sk.e64t[n];               // uniform broadcast
        float2 Wn = sk.W2[w][n];             // uniform broadcast
        float vr = Wn.x * Pr - Wn.y * Pi;
        float vi = Wn.x * Pi + Wn.y * Pr;
        #pragma unroll
        for (int j = 0; j < 8; ++j) {
            kacc[j] += vr;
            float tr = vr * E.x - vi * E.y;
            vi = vr * E.y + vi * E.x; vr = tr;
        }
    }
    // -- store transposed + reversed --
    #pragma unroll
    for (int j = 0; j < 8; ++j) {
        int l = w * 512 + j * 64 + lane;
        Ktrev[(long)(LL - 1 - l) * HH + h] = kacc[j];
    }
}

// k2: fused gather-conv -- no u materialization. Block = (b, 32-token
// chunk). Stage Ktrev slice [32][256] linearly via global_load_lds (LDS
// read Kls[l*256+t]: lanes consecutive -> conflict-free); stream emb rows
// coalesced; 32 FMA/thread; one atomicAdd per thread into y[b][h].
__global__ __launch_bounds__(256) void gconv_kernel(
    const int* __restrict__ ids, const float* __restrict__ emb,
    const float* __restrict__ Ktrev, float* __restrict__ y) {
    __shared__ float Kls[TK * HH];   // 32 KB
    __shared__ int idsl[TK];
    int t = threadIdx.x;
    int b = blockIdx.x >> 7;
    int c = blockIdx.x & (NCH - 1);
    int i0 = c * TK;
    int wv = t >> 6, lane = t & 63;
    if (t < TK) idsl[t] = ids[b * LL + i0 + t];
    // wave wv stages rows [8wv, 8wv+8): one global_load_lds (1KB) per row
    {
        const float* src = Ktrev + (long)i0 * HH;
        #pragma unroll
        for (int r = 0; r < 8; ++r) {
            int row = wv * 8 + r;
            __builtin_amdgcn_global_load_lds(
                (const __attribute__((address_space(1))) void*)
                    (src + row * HH + lane * 4),
                (__attribute__((address_space(3))) void*)(&Kls[row * HH]),
                16, 0, 0);
        }
    }
    __syncthreads();   // drains vmcnt + lgkmcnt
    float acc = 0.0f;
    #pragma unroll 8
    for (int l = 0; l < TK; ++l) {
        int id = idsl[l];                        // uniform LDS broadcast
        float v = emb[(long)id * HH + t];        // coalesced 1KB/256thr
        acc = fmaf(v, Kls[l * HH + t], acc);     // conflict-free ds_read
    }
    atomicAdd(&y[b * HH + t], acc);              // device-scope f32 atomic
}

// k3: output projection + GLU (R7's proven 1024-block shape). Each block
// owns (b, 2 h's); recomputes the cheap GELU row locally from y.
__global__ __launch_bounds__(256) void out_kernel(
    const float* __restrict__ y, const int* __restrict__ ids,
    const float* __restrict__ emb, const float* __restrict__ Dv,
    const float* __restrict__ W, const float* __restrict__ bvec,
    float* __restrict__ out) {
    int b = blockIdx.x >> 7;
    int tile = blockIdx.x & 127;
    int t = threadIdx.x;
    int w = t >> 6, lane = t & 63;
    __shared__ float gs[HH];
    __shared__ float zb[4];
    int idl = ids[b * LL + LL - 1];              // uniform scalar
    float yv = y[b * HH + t] + emb[(long)idl * HH + t] * Dv[t];
    gs[t] = 0.5f * yv * (1.0f + erff(yv * 0.70710678118654752f));
    __syncthreads();
    int hh = tile * 2 + (w >> 1);
    int o = (w & 1) * HH + hh;
    float4 wv4 = ((const float4*)(W + o * HH))[lane];
    float4 gv4 = ((const float4*)gs)[lane];
    float p = wv4.x * gv4.x + wv4.y * gv4.y + wv4.z * gv4.z + wv4.w * gv4.w;
    #pragma unroll
    for (int m = 32; m > 0; m >>= 1) p += __shfl_xor(p, m);
    if (lane == 0) zb[w] = p + bvec[o];
    __syncthreads();
    if (t < 2) {
        int hq = tile * 2 + t;
        float z1 = zb[t * 2 + 0];
        float z2 = zb[t * 2 + 1];
        out[b * HH + hq] = z1 * (1.0f / (1.0f + expf(-z2)));
    }
}

extern "C" void kernel_launch(void* const* d_in, const int* in_sizes, int n_in,
                              void* d_out, int out_size, void* d_ws, size_t ws_size,
                              hipStream_t stream) {
    const int* input_ids = (const int*)d_in[0];
    const float* embedding = (const float*)d_in[1];
    const float* log_dt = (const float*)d_in[2];
    const float* A_log_re = (const float*)d_in[3];
    const float* A_im = (const float*)d_in[4];
    const float* B_re = (const float*)d_in[5];
    const float* B_im = (const float*)d_in[6];
    const float* C_re = (const float*)d_in[7];
    const float* C_im = (const float*)d_in[8];
    const float* D = (const float*)d_in[9];
    const float* W_out = (const float*)d_in[10];
    const float* b_out = (const float*)d_in[11];
    float* out = (float*)d_out;

    float* ws = (float*)d_ws;
    float* Ktrev = ws;                            // L*H floats
    float* y = ws + 1048576;                      // B*H floats

    kmat_kernel<<<HH, 512, 0, stream>>>(
        log_dt, A_log_re, A_im, B_re, B_im, C_re, C_im, Ktrev, y);

    gconv_kernel<<<BB * NCH, 256, 0, stream>>>(
        input_ids, embedding, Ktrev, y);

    out_kernel<<<BB * 128, 256, 0, stream>>>(
        y, input_ids, embedding, D, W_out, b_out, out);
}